// Round 1
// baseline (637.770 us; speedup 1.0000x reference)
//
#include <hip/hip_runtime.h>
#include <math.h>

#define C_DIM 256
#define CI_DIM 128
#define HW_DIM 4096
#define NB 4
#define EPSV 1e-5f

typedef __attribute__((ext_vector_type(8))) short bf16x8;
typedef __attribute__((ext_vector_type(4))) float f32x4;

static __device__ __forceinline__ unsigned short f2bf(float f) {
  unsigned u = __float_as_uint(f);
  u += 0x7fffu + ((u >> 16) & 1u);
  return (unsigned short)(u >> 16);
}
static __device__ __forceinline__ float bf2f(unsigned short h) {
  return __uint_as_float(((unsigned)h) << 16);
}
// XOR swizzle for 256B-row and 128B-row LDS tiles (breaks 16-way ds_read_b128 conflicts)
static __device__ __forceinline__ int swz256o(int row, int cb) {
  return row * 256 + (cb ^ ((row & 7) << 4));
}
static __device__ __forceinline__ int swz128o(int row, int cb) {
  return row * 128 + (cb ^ ((row & 7) << 4));
}

// ---------------- projections: out[pr][n][o][p] = sum_c w[o][c]*src[n][c][p] + b[o]
__global__ __launch_bounds__(256) void proj_kernel(
    const float* __restrict__ x, const float* __restrict__ y,
    const float* __restrict__ tw, const float* __restrict__ tb,
    const float* __restrict__ pw, const float* __restrict__ pb,
    const float* __restrict__ gw, const float* __restrict__ gb,
    float* __restrict__ proj) {
  const int ptile = blockIdx.x;   // 16 tiles of 256 positions
  const int otile = blockIdx.y;   // 16 tiles of 8 out-channels
  const int z = blockIdx.z;       // 12 = 3 proj * 4 batch
  const int pr = z >> 2, n = z & 3;
  const float* src = (pr == 1) ? y : x;
  const float* w = (pr == 0) ? tw : (pr == 1 ? pw : gw);
  const float* b = (pr == 0) ? tb : (pr == 1 ? pb : gb);
  __shared__ float wl[8][C_DIM];
  for (int e = threadIdx.x; e < 8 * C_DIM; e += 256)
    wl[e >> 8][e & 255] = w[(size_t)(otile * 8 + (e >> 8)) * C_DIM + (e & 255)];
  __syncthreads();
  const int p = ptile * 256 + threadIdx.x;
  const float* sp = src + (size_t)n * C_DIM * HW_DIM + p;
  float acc[8] = {0.f, 0.f, 0.f, 0.f, 0.f, 0.f, 0.f, 0.f};
#pragma unroll 4
  for (int c = 0; c < C_DIM; ++c) {
    float xv = sp[(size_t)c * HW_DIM];
#pragma unroll
    for (int o = 0; o < 8; ++o) acc[o] += wl[o][c] * xv;
  }
  float* op = proj + ((size_t)(pr * NB + n) * CI_DIM + otile * 8) * HW_DIM + p;
#pragma unroll
  for (int o = 0; o < 8; ++o) op[(size_t)o * HW_DIM] = acc[o] + b[otile * 8 + o];
}

// ---------------- flash attention; hi/lo bf16 split on QK^T, bf16 PV
__global__ __launch_bounds__(256) void attn_kernel(const float* __restrict__ proj,
                                                   float* __restrict__ o_ws) {
  const int lin = blockIdx.x;           // 256 blocks
  const int xcd = lin & 7;              // XCD-aware: each XCD serves one batch
  const int n = xcd >> 1;
  const int qt = ((lin >> 3) << 1) | (xcd & 1);
  const int q0 = qt * 64;
  const int tid = threadIdx.x;
  const int wv = tid >> 6;              // wave 0..3, 16 q-rows each
  const int lane = tid & 63;
  const int lg = lane >> 4;             // 0..3
  const int lr = lane & 15;             // 0..15

  const float* theta = proj + (size_t)(0 * NB + n) * CI_DIM * HW_DIM;
  const float* phi   = proj + (size_t)(1 * NB + n) * CI_DIM * HW_DIM;
  const float* gp    = proj + (size_t)(2 * NB + n) * CI_DIM * HW_DIM;

  __shared__ unsigned short khi[64 * CI_DIM];   // [kpos][ci] 16KB
  __shared__ unsigned short klo[64 * CI_DIM];   // 16KB
  __shared__ unsigned short gt[CI_DIM * 64];    // [ci][kpos] 16KB
  __shared__ unsigned short pt[4][16 * 64];     // per-wave P tile 2KB

  // Q fragments in registers: A[q=lr][ci = ch*32 + lg*8 + j], hi and lo
  bf16x8 qh[4], ql[4];
#pragma unroll
  for (int ch = 0; ch < 4; ++ch) {
#pragma unroll
    for (int j = 0; j < 8; ++j) {
      int ci = ch * 32 + lg * 8 + j;
      float qv = theta[(size_t)ci * HW_DIM + q0 + wv * 16 + lr];
      unsigned short h = f2bf(qv);
      qh[ch][j] = (short)h;
      ql[ch][j] = (short)f2bf(qv - bf2f(h));
    }
  }

  f32x4 acc[8];
#pragma unroll
  for (int of = 0; of < 8; ++of) acc[of] = f32x4{0.f, 0.f, 0.f, 0.f};
  float mrow[4] = {-INFINITY, -INFINITY, -INFINITY, -INFINITY};
  float lrow[4] = {0.f, 0.f, 0.f, 0.f};
  unsigned short* ptw = &pt[wv][0];

  for (int kt = 0; kt < 64; ++kt) {
    const int k0 = kt * 64;
    __syncthreads();  // previous iteration's reads complete before restage
    for (int e = tid; e < 64 * CI_DIM; e += 256) {
      int ci = e >> 6;
      int kk = e & 63;
      float pv = phi[(size_t)ci * HW_DIM + k0 + kk];
      unsigned short ph = f2bf(pv);
      unsigned short pl = f2bf(pv - bf2f(ph));
      int ko = swz256o(kk, ci * 2);
      *(unsigned short*)((char*)khi + ko) = ph;
      *(unsigned short*)((char*)klo + ko) = pl;
      float gv = gp[(size_t)ci * HW_DIM + k0 + kk];
      *(unsigned short*)((char*)gt + swz128o(ci, kk * 2)) = f2bf(gv);
    }
    __syncthreads();

    // S = Qhi*Khi + Qhi*Klo + Qlo*Khi   (fp32-accurate scores)
    f32x4 s[4];
#pragma unroll
    for (int cf = 0; cf < 4; ++cf) s[cf] = f32x4{0.f, 0.f, 0.f, 0.f};
#pragma unroll
    for (int ch = 0; ch < 4; ++ch) {
#pragma unroll
      for (int cf = 0; cf < 4; ++cf) {
        bf16x8 kh = *(const bf16x8*)((const char*)khi + swz256o(cf * 16 + lr, (ch * 32 + lg * 8) * 2));
        bf16x8 kl = *(const bf16x8*)((const char*)klo + swz256o(cf * 16 + lr, (ch * 32 + lg * 8) * 2));
        s[cf] = __builtin_amdgcn_mfma_f32_16x16x32_bf16(qh[ch], kh, s[cf], 0, 0, 0);
        s[cf] = __builtin_amdgcn_mfma_f32_16x16x32_bf16(qh[ch], kl, s[cf], 0, 0, 0);
        s[cf] = __builtin_amdgcn_mfma_f32_16x16x32_bf16(ql[ch], kh, s[cf], 0, 0, 0);
      }
    }

    // online softmax; D layout: row = lg*4 + r, col = cf*16 + lr
#pragma unroll
    for (int r = 0; r < 4; ++r) {
      float v0 = s[0][r], v1 = s[1][r], v2 = s[2][r], v3 = s[3][r];
      float mx = fmaxf(fmaxf(v0, v1), fmaxf(v2, v3));
      mx = fmaxf(mx, __shfl_xor(mx, 1));
      mx = fmaxf(mx, __shfl_xor(mx, 2));
      mx = fmaxf(mx, __shfl_xor(mx, 4));
      mx = fmaxf(mx, __shfl_xor(mx, 8));
      float mnew = fmaxf(mrow[r], mx);
      float scf = __expf(mrow[r] - mnew);   // 0 on first tile (-inf)
      float p0 = __expf(v0 - mnew);
      float p1 = __expf(v1 - mnew);
      float p2 = __expf(v2 - mnew);
      float p3 = __expf(v3 - mnew);
      float sum = p0 + p1 + p2 + p3;
      sum += __shfl_xor(sum, 1);
      sum += __shfl_xor(sum, 2);
      sum += __shfl_xor(sum, 4);
      sum += __shfl_xor(sum, 8);
      lrow[r] = lrow[r] * scf + sum;
      mrow[r] = mnew;
#pragma unroll
      for (int of = 0; of < 8; ++of) acc[of][r] *= scf;
      int rl = lg * 4 + r;
      *(unsigned short*)((char*)ptw + swz128o(rl, (0 * 16 + lr) * 2)) = f2bf(p0);
      *(unsigned short*)((char*)ptw + swz128o(rl, (1 * 16 + lr) * 2)) = f2bf(p1);
      *(unsigned short*)((char*)ptw + swz128o(rl, (2 * 16 + lr) * 2)) = f2bf(p2);
      *(unsigned short*)((char*)ptw + swz128o(rl, (3 * 16 + lr) * 2)) = f2bf(p3);
    }
    __syncthreads();  // P visible before PV reads

    // O += P * G
#pragma unroll
    for (int kc = 0; kc < 2; ++kc) {
      bf16x8 pa = *(const bf16x8*)((const char*)ptw + swz128o(lr, (kc * 32 + lg * 8) * 2));
#pragma unroll
      for (int of = 0; of < 8; ++of) {
        bf16x8 gb = *(const bf16x8*)((const char*)gt + swz128o(of * 16 + lr, (kc * 32 + lg * 8) * 2));
        acc[of] = __builtin_amdgcn_mfma_f32_16x16x32_bf16(pa, gb, acc[of], 0, 0, 0);
      }
    }
  }

  // epilogue: o_ws[n][q][ci] = acc / l
#pragma unroll
  for (int of = 0; of < 8; ++of) {
#pragma unroll
    for (int r = 0; r < 4; ++r) {
      int q = q0 + wv * 16 + lg * 4 + r;
      o_ws[((size_t)n * HW_DIM + q) * CI_DIM + of * 16 + lr] = acc[of][r] / lrow[r];
    }
  }
}

// ---------------- rec projection + BN partial stats; writes rec result into d_out
__global__ __launch_bounds__(256) void rec_kernel(
    const float* __restrict__ o_ws, const float* __restrict__ rw,
    const float* __restrict__ rb, float* __restrict__ out,
    float* __restrict__ stats) {
  const int pblk = blockIdx.x;  // 64 tiles of 64 positions
  const int n = blockIdx.y;     // 4
  const int c = threadIdx.x;    // channel 0..255
  __shared__ float4 ot4[64 * 32];  // [p][ci/4] 32KB
  const float4* src4 = (const float4*)(o_ws + ((size_t)n * HW_DIM + pblk * 64) * CI_DIM);
  for (int e = threadIdx.x; e < 64 * 32; e += 256) ot4[e] = src4[e];
  __syncthreads();
  float4 wr[32];
  const float4* w4 = (const float4*)(rw + (size_t)c * CI_DIM);
#pragma unroll
  for (int i = 0; i < 32; ++i) wr[i] = w4[i];
  const float bias = rb[c];
  float sum = 0.f, sumsq = 0.f;
  float* op = out + ((size_t)n * C_DIM + c) * HW_DIM + pblk * 64;
  for (int p = 0; p < 64; ++p) {
    float a = 0.f;
#pragma unroll
    for (int i = 0; i < 32; ++i) {
      float4 ov = ot4[p * 32 + i];  // uniform address -> LDS broadcast
      a += wr[i].x * ov.x + wr[i].y * ov.y + wr[i].z * ov.z + wr[i].w * ov.w;
    }
    a += bias;
    op[p] = a;
    sum += a;
    sumsq += a * a;
  }
  atomicAdd(&stats[c], sum);
  atomicAdd(&stats[C_DIM + c], sumsq);
}

// ---------------- BN apply + residual, in place on d_out
__global__ __launch_bounds__(256) void bn_kernel(
    const float* __restrict__ x, const float* __restrict__ gamma,
    const float* __restrict__ beta, const float* __restrict__ stats,
    float* __restrict__ out) {
  const size_t i4 = (size_t)blockIdx.x * 256 + threadIdx.x;  // 1048576 float4s
  const int c = (int)((i4 >> 10) & 255);
  const float inv = 1.f / 16384.f;
  const float mean = stats[c] * inv;
  const float var = stats[C_DIM + c] * inv - mean * mean;
  const float gm = gamma[c] * rsqrtf(var + EPSV);
  const float bt = beta[c];
  float4 rv = ((const float4*)out)[i4];
  float4 xv = ((const float4*)x)[i4];
  float4 o;
  o.x = xv.x + (rv.x - mean) * gm + bt;
  o.y = xv.y + (rv.y - mean) * gm + bt;
  o.z = xv.z + (rv.z - mean) * gm + bt;
  o.w = xv.w + (rv.w - mean) * gm + bt;
  ((float4*)out)[i4] = o;
}

extern "C" void kernel_launch(void* const* d_in, const int* in_sizes, int n_in,
                              void* d_out, int out_size, void* d_ws, size_t ws_size,
                              hipStream_t stream) {
  const float* x  = (const float*)d_in[0];
  const float* y  = (const float*)d_in[1];
  const float* tw = (const float*)d_in[2];
  const float* tb = (const float*)d_in[3];
  const float* pw = (const float*)d_in[4];
  const float* pb = (const float*)d_in[5];
  const float* gw = (const float*)d_in[6];
  const float* gb = (const float*)d_in[7];
  const float* rw = (const float*)d_in[8];
  const float* rb = (const float*)d_in[9];
  const float* gamma = (const float*)d_in[10];
  const float* beta  = (const float*)d_in[11];
  float* out = (float*)d_out;
  float* ws = (float*)d_ws;
  float* proj  = ws;                                         // 3*4*128*4096 f32 (24MB)
  float* o_ws  = ws + (size_t)3 * NB * CI_DIM * HW_DIM;      // 4*4096*128 f32 (8MB)
  float* stats = o_ws + (size_t)NB * HW_DIM * CI_DIM;        // 512 f32
  hipMemsetAsync(stats, 0, 2 * C_DIM * sizeof(float), stream);
  proj_kernel<<<dim3(16, 16, 12), 256, 0, stream>>>(x, y, tw, tb, pw, pb, gw, gb, proj);
  attn_kernel<<<dim3(256), 256, 0, stream>>>(proj, o_ws);
  rec_kernel<<<dim3(64, 4), 256, 0, stream>>>(o_ws, rw, rb, out, stats);
  bn_kernel<<<dim3(4096), 256, 0, stream>>>(x, gamma, beta, stats, out);
}

// Round 2
// 298.610 us; speedup vs baseline: 2.1358x; 2.1358x over previous
//
#include <hip/hip_runtime.h>
#include <math.h>

#define C_DIM 256
#define CI_DIM 128
#define HW_DIM 4096
#define NB 4
#define EPSV 1e-5f

typedef __attribute__((ext_vector_type(8))) _Float16 f16x8;
typedef __attribute__((ext_vector_type(4))) float f32x4;

typedef __attribute__((address_space(1))) const unsigned int as1_u32;
typedef __attribute__((address_space(3))) unsigned int as3_u32;

// ---------------- projections: out[pr][n][o][p] = sum_c w[o][c]*src[n][c][p] + b[o]
__global__ __launch_bounds__(256) void proj_kernel(
    const float* __restrict__ x, const float* __restrict__ y,
    const float* __restrict__ tw, const float* __restrict__ tb,
    const float* __restrict__ pw, const float* __restrict__ pb,
    const float* __restrict__ gw, const float* __restrict__ gb,
    float* __restrict__ proj) {
  const int ptile = blockIdx.x;   // 16 tiles of 256 positions
  const int otile = blockIdx.y;   // 16 tiles of 8 out-channels
  const int z = blockIdx.z;       // 12 = 3 proj * 4 batch
  const int pr = z >> 2, n = z & 3;
  const float* src = (pr == 1) ? y : x;
  const float* w = (pr == 0) ? tw : (pr == 1 ? pw : gw);
  const float* b = (pr == 0) ? tb : (pr == 1 ? pb : gb);
  __shared__ float wl[8][C_DIM];
  for (int e = threadIdx.x; e < 8 * C_DIM; e += 256)
    wl[e >> 8][e & 255] = w[(size_t)(otile * 8 + (e >> 8)) * C_DIM + (e & 255)];
  __syncthreads();
  const int p = ptile * 256 + threadIdx.x;
  const float* sp = src + (size_t)n * C_DIM * HW_DIM + p;
  float acc[8] = {0.f, 0.f, 0.f, 0.f, 0.f, 0.f, 0.f, 0.f};
#pragma unroll 4
  for (int c = 0; c < C_DIM; ++c) {
    float xv = sp[(size_t)c * HW_DIM];
#pragma unroll
    for (int o = 0; o < 8; ++o) acc[o] += wl[o][c] * xv;
  }
  float* op = proj + ((size_t)(pr * NB + n) * CI_DIM + otile * 8) * HW_DIM + p;
#pragma unroll
  for (int o = 0; o < 8; ++o) op[(size_t)o * HW_DIM] = acc[o] + b[otile * 8 + o];
}

// ---------------- pack phi: fp32 [n][ci][pos] -> fp16 transposed [n][pos][ci]
__global__ __launch_bounds__(256) void pack_phi(const float* __restrict__ phi,
                                                _Float16* __restrict__ phi_t) {
  const int n = blockIdx.y;
  const int chunk = blockIdx.x * 256 + threadIdx.x;  // 65536 per n
  const int p = chunk & 4095;
  const int c8 = chunk >> 12;  // 0..15
  const float* src = phi + (size_t)n * CI_DIM * HW_DIM + (size_t)(c8 * 8) * HW_DIM + p;
  f16x8 v;
#pragma unroll
  for (int j = 0; j < 8; ++j) v[j] = (_Float16)src[(size_t)j * HW_DIM];
  *(f16x8*)((char*)(phi_t + (size_t)n * HW_DIM * CI_DIM) + p * 256 + c8 * 16) = v;
}

// ---------------- pack g: fp32 -> fp16, same layout [n][ci][pos]
__global__ __launch_bounds__(256) void pack_g(const float* __restrict__ g,
                                              _Float16* __restrict__ g16) {
  size_t i = ((size_t)blockIdx.x * 256 + threadIdx.x) * 8;
  f32x4 a = *(const f32x4*)(g + i);
  f32x4 b = *(const f32x4*)(g + i + 4);
  f16x8 v;
#pragma unroll
  for (int j = 0; j < 4; ++j) { v[j] = (_Float16)a[j]; v[4 + j] = (_Float16)b[j]; }
  *(f16x8*)(g16 + i) = v;
}

// ---------------- flash attention, fp16 MFMA, 3-buffer pipelined staging
__global__ __launch_bounds__(256) void attn_kernel(
    const _Float16* __restrict__ phi_t, const _Float16* __restrict__ g16,
    const float* __restrict__ proj, float* __restrict__ o_ws) {
  const int lin = blockIdx.x;  // 256 blocks
  const int xcd = lin & 7;     // XCD-aware: 2 XCDs per batch
  const int n = xcd >> 1;
  const int qt = ((lin >> 3) << 1) | (xcd & 1);
  const int q0 = qt * 64;
  const int tid = threadIdx.x;
  const int wv = tid >> 6;
  const int lane = tid & 63;
  const int lg = lane >> 4;
  const int lr = lane & 15;

  // smem: 3 bufs x {K 16KB [kk][ci-swz], G 16KB [ci][k-swz]} + P 4x2KB
  __shared__ __align__(16) char smem[3 * 32768 + 4 * 2048];

  const float* theta = proj + (size_t)n * CI_DIM * HW_DIM;
  const char* phin = (const char*)(phi_t + (size_t)n * HW_DIM * CI_DIM);
  const char* g16n = (const char*)(g16 + (size_t)n * CI_DIM * HW_DIM);

  // pre-swizzled per-thread staging source bases (rule #21: linear LDS dest,
  // inverse-swizzled global source, swizzled LDS reads)
  const char* pK0 = phin + (tid >> 4) * 256 + (((tid & 15) * 16) ^ (((tid >> 4) & 7) << 4));
  const char* pG0 = g16n + (size_t)(tid >> 3) * (HW_DIM * 2) +
                    (((tid & 7) * 16) ^ (((tid >> 3) & 7) << 4));

  // Q fragment (fp16): A[row=q=lr][k=ci=ch*32+lg*8+j]
  f16x8 qf[4];
#pragma unroll
  for (int ch = 0; ch < 4; ++ch)
#pragma unroll
    for (int j = 0; j < 8; ++j)
      qf[ch][j] = (_Float16)theta[(size_t)(ch * 32 + lg * 8 + j) * HW_DIM + q0 + wv * 16 + lr];

  const int xorv = (lr & 7) << 4;
  int cbx[4];
#pragma unroll
  for (int ch = 0; ch < 4; ++ch) cbx[ch] = (ch * 64 + lg * 16) ^ xorv;

  char* pB = smem + 3 * 32768 + wv * 2048;

#define STAGE(KT1, BJ)                                                                   \
  do {                                                                                   \
    char* kdst = smem + (BJ) * 32768 + wv * 1024;                                        \
    char* gdst = kdst + 16384;                                                           \
    const char* ks = pK0 + (KT1) * 16384;                                                \
    const char* gs = pG0 + (KT1) * 128;                                                  \
    _Pragma("unroll") for (int i = 0; i < 4; ++i)                                        \
        __builtin_amdgcn_global_load_lds((as1_u32*)(ks + i * 4096),                      \
                                         (as3_u32*)(kdst + i * 4096), 16, 0, 0);         \
    _Pragma("unroll") for (int i = 0; i < 4; ++i)                                        \
        __builtin_amdgcn_global_load_lds((as1_u32*)(gs + i * 262144),                    \
                                         (as3_u32*)(gdst + i * 4096), 16, 0, 0);         \
  } while (0)

#define QK_COMPUTE(SD, KBASE)                                                            \
  do {                                                                                   \
    _Pragma("unroll") for (int cf = 0; cf < 4; ++cf) {                                   \
      const char* krow = (KBASE) + (cf * 16 + lr) * 256;                                 \
      f32x4 sv = f32x4{0.f, 0.f, 0.f, 0.f};                                              \
      _Pragma("unroll") for (int ch = 0; ch < 4; ++ch) {                                 \
        f16x8 kf = *(const f16x8*)(krow + cbx[ch]);                                      \
        sv = __builtin_amdgcn_mfma_f32_16x16x32_f16(qf[ch], kf, sv, 0, 0, 0);            \
      }                                                                                  \
      SD[cf] = sv;                                                                       \
    }                                                                                    \
  } while (0)

  f32x4 acc[8];
#pragma unroll
  for (int of = 0; of < 8; ++of) acc[of] = f32x4{0.f, 0.f, 0.f, 0.f};
  float mrow[4] = {-INFINITY, -INFINITY, -INFINITY, -INFINITY};
  float lrow[4] = {0.f, 0.f, 0.f, 0.f};

  STAGE(0, 0);
  STAGE(1, 1);
  __syncthreads();  // tiles 0,1 landed

  f32x4 s_cur[4];
  QK_COMPUTE(s_cur, smem);

  for (int kt = 0; kt < 64; ++kt) {
    const int bj = kt % 3;
    if (kt < 62) STAGE(kt + 2, (kt + 2) % 3);  // into buffer freed by last barrier
    f32x4 s_next[4];
#pragma unroll
    for (int cf = 0; cf < 4; ++cf) s_next[cf] = f32x4{0.f, 0.f, 0.f, 0.f};
    if (kt < 63) {
      const char* kb = smem + ((kt + 1) % 3) * 32768;
      QK_COMPUTE(s_next, kb);  // MFMA, overlaps softmax VALU below
    }

    // online softmax on s_cur; layout: row q = lg*4+r, col k = cf*16+lr
    float scfa[4];
#pragma unroll
    for (int r = 0; r < 4; ++r) {
      float v0 = s_cur[0][r], v1 = s_cur[1][r], v2 = s_cur[2][r], v3 = s_cur[3][r];
      float mx = fmaxf(fmaxf(v0, v1), fmaxf(v2, v3));
      mx = fmaxf(mx, __shfl_xor(mx, 1));
      mx = fmaxf(mx, __shfl_xor(mx, 2));
      mx = fmaxf(mx, __shfl_xor(mx, 4));
      mx = fmaxf(mx, __shfl_xor(mx, 8));
      float mnew = fmaxf(mrow[r], mx);
      float sc = __expf(mrow[r] - mnew);
      float p0 = __expf(v0 - mnew);
      float p1 = __expf(v1 - mnew);
      float p2 = __expf(v2 - mnew);
      float p3 = __expf(v3 - mnew);
      float sm = p0 + p1 + p2 + p3;
      sm += __shfl_xor(sm, 1);
      sm += __shfl_xor(sm, 2);
      sm += __shfl_xor(sm, 4);
      sm += __shfl_xor(sm, 8);
      lrow[r] = lrow[r] * sc + sm;
      mrow[r] = mnew;
      scfa[r] = sc;
      const int rl = lg * 4 + r;
      const int xp = (rl & 7) << 4;
      char* prow = pB + rl * 128;
      *(_Float16*)(prow + ((lr * 2) ^ xp)) = (_Float16)p0;
      *(_Float16*)(prow + ((32 + lr * 2) ^ xp)) = (_Float16)p1;
      *(_Float16*)(prow + ((64 + lr * 2) ^ xp)) = (_Float16)p2;
      *(_Float16*)(prow + ((96 + lr * 2) ^ xp)) = (_Float16)p3;
    }
    // broadcast rescale factor of q-row lr to all its lanes (O^T layout: col=q=lr)
    float sel = (lr & 2) ? ((lr & 1) ? scfa[3] : scfa[2]) : ((lr & 1) ? scfa[1] : scfa[0]);
    float scq = __shfl(sel, ((lr >> 2) << 4) | (lr & 3));
#pragma unroll
    for (int of = 0; of < 8; ++of) acc[of] *= scq;

    // PV: O^T = G * P^T ; A=G[ci][k] (natural layout), B=P[q][k]
    {
      const char* gbuf = smem + bj * 32768 + 16384;
#pragma unroll
      for (int kc = 0; kc < 2; ++kc) {
        f16x8 pf = *(const f16x8*)(pB + lr * 128 + cbx[kc]);
#pragma unroll
        for (int of = 0; of < 8; ++of) {
          f16x8 gf = *(const f16x8*)(gbuf + (of * 16 + lr) * 128 + cbx[kc]);
          acc[of] = __builtin_amdgcn_mfma_f32_16x16x32_f16(gf, pf, acc[of], 0, 0, 0);
        }
      }
    }
    __syncthreads();  // frees buf bj; drains stage(kt+2)
#pragma unroll
    for (int cf = 0; cf < 4; ++cf) s_cur[cf] = s_next[cf];
  }

  // epilogue: transpose O^T through LDS, coalesced store o_ws[n][q][ci]
  float lsel = (lr & 2) ? ((lr & 1) ? lrow[3] : lrow[2]) : ((lr & 1) ? lrow[1] : lrow[0]);
  float lq = __shfl(lsel, ((lr >> 2) << 4) | (lr & 3));
  float inv = 1.0f / lq;
  float* ep = (float*)(smem + wv * 8448);  // 16 rows x 132 f32 (528B, 16-aligned)
#pragma unroll
  for (int of = 0; of < 8; ++of)
#pragma unroll
    for (int r = 0; r < 4; ++r)
      ep[lr * 132 + of * 16 + lg * 4 + r] = acc[of][r] * inv;
#pragma unroll
  for (int it = 0; it < 8; ++it) {
    int e = lane + it * 64;
    int q = e >> 5, c4 = e & 31;
    f32x4 v = *(const f32x4*)(ep + q * 132 + c4 * 4);
    *(f32x4*)(o_ws + ((size_t)n * HW_DIM + q0 + wv * 16 + q) * CI_DIM + c4 * 4) = v;
  }
#undef STAGE
#undef QK_COMPUTE
}

// ---------------- rec projection + BN partial stats; writes rec result into d_out
__global__ __launch_bounds__(256) void rec_kernel(
    const float* __restrict__ o_ws, const float* __restrict__ rw,
    const float* __restrict__ rb, float* __restrict__ out,
    float* __restrict__ stats) {
  const int pblk = blockIdx.x;  // 64 tiles of 64 positions
  const int n = blockIdx.y;     // 4
  const int c = threadIdx.x;    // channel 0..255
  __shared__ float4 ot4[64 * 32];  // [p][ci/4] 32KB
  const float4* src4 = (const float4*)(o_ws + ((size_t)n * HW_DIM + pblk * 64) * CI_DIM);
  for (int e = threadIdx.x; e < 64 * 32; e += 256) ot4[e] = src4[e];
  __syncthreads();
  float4 wr[32];
  const float4* w4 = (const float4*)(rw + (size_t)c * CI_DIM);
#pragma unroll
  for (int i = 0; i < 32; ++i) wr[i] = w4[i];
  const float bias = rb[c];
  float sum = 0.f, sumsq = 0.f;
  float* op = out + ((size_t)n * C_DIM + c) * HW_DIM + pblk * 64;
  for (int p = 0; p < 64; ++p) {
    float a = 0.f;
#pragma unroll
    for (int i = 0; i < 32; ++i) {
      float4 ov = ot4[p * 32 + i];  // uniform address -> LDS broadcast
      a += wr[i].x * ov.x + wr[i].y * ov.y + wr[i].z * ov.z + wr[i].w * ov.w;
    }
    a += bias;
    op[p] = a;
    sum += a;
    sumsq += a * a;
  }
  atomicAdd(&stats[c], sum);
  atomicAdd(&stats[C_DIM + c], sumsq);
}

// ---------------- BN apply + residual, in place on d_out
__global__ __launch_bounds__(256) void bn_kernel(
    const float* __restrict__ x, const float* __restrict__ gamma,
    const float* __restrict__ beta, const float* __restrict__ stats,
    float* __restrict__ out) {
  const size_t i4 = (size_t)blockIdx.x * 256 + threadIdx.x;  // 1048576 float4s
  const int c = (int)((i4 >> 10) & 255);
  const float inv = 1.f / 16384.f;
  const float mean = stats[c] * inv;
  const float var = stats[C_DIM + c] * inv - mean * mean;
  const float gm = gamma[c] * rsqrtf(var + EPSV);
  const float bt = beta[c];
  float4 rv = ((const float4*)out)[i4];
  float4 xv = ((const float4*)x)[i4];
  float4 o;
  o.x = xv.x + (rv.x - mean) * gm + bt;
  o.y = xv.y + (rv.y - mean) * gm + bt;
  o.z = xv.z + (rv.z - mean) * gm + bt;
  o.w = xv.w + (rv.w - mean) * gm + bt;
  ((float4*)out)[i4] = o;
}

extern "C" void kernel_launch(void* const* d_in, const int* in_sizes, int n_in,
                              void* d_out, int out_size, void* d_ws, size_t ws_size,
                              hipStream_t stream) {
  const float* x  = (const float*)d_in[0];
  const float* y  = (const float*)d_in[1];
  const float* tw = (const float*)d_in[2];
  const float* tb = (const float*)d_in[3];
  const float* pw = (const float*)d_in[4];
  const float* pb = (const float*)d_in[5];
  const float* gw = (const float*)d_in[6];
  const float* gb = (const float*)d_in[7];
  const float* rw = (const float*)d_in[8];
  const float* rb = (const float*)d_in[9];
  const float* gamma = (const float*)d_in[10];
  const float* beta  = (const float*)d_in[11];
  float* out = (float*)d_out;
  float* ws = (float*)d_ws;
  float* proj = ws;                                    // 3*4*128*4096 f32 (24MB)
  _Float16* phi_t = (_Float16*)(ws + 6291456);         // 4MB fp16 [n][pos][ci]
  _Float16* g16 = phi_t + 2097152;                     // 4MB fp16 [n][ci][pos]
  float* o_ws = (float*)(g16 + 2097152);               // 8MB f32 [n][q][ci]
  float* stats = o_ws + 2097152;                       // 512 f32
  hipMemsetAsync(stats, 0, 2 * C_DIM * sizeof(float), stream);
  proj_kernel<<<dim3(16, 16, 12), 256, 0, stream>>>(x, y, tw, tb, pw, pb, gw, gb, proj);
  pack_phi<<<dim3(256, NB), 256, 0, stream>>>(proj + (size_t)4 * 524288, phi_t);
  pack_g<<<dim3(1024), 256, 0, stream>>>(proj + (size_t)8 * 524288, g16);
  attn_kernel<<<dim3(256), 256, 0, stream>>>(phi_t, g16, proj, o_ws);
  rec_kernel<<<dim3(64, 4), 256, 0, stream>>>(o_ws, rw, rb, out, stats);
  bn_kernel<<<dim3(4096), 256, 0, stream>>>(x, gamma, beta, stats, out);
}

// Round 3
// 245.977 us; speedup vs baseline: 2.5928x; 1.2140x over previous
//
#include <hip/hip_runtime.h>
#include <math.h>

#define C_DIM 256
#define CI_DIM 128
#define HW_DIM 4096
#define NB 4
#define EPSV 1e-5f

typedef __attribute__((ext_vector_type(8))) _Float16 f16x8;
typedef __attribute__((ext_vector_type(4))) float f32x4;

typedef __attribute__((address_space(1))) const unsigned int as1_u32;
typedef __attribute__((address_space(3))) unsigned int as3_u32;

// ---------------- projections -> fp16 outputs in attn-ready layouts
// theta/phi: [n][pos][ci] fp16 ; g: [n][ci][pos] fp16
__global__ __launch_bounds__(256) void proj_kernel(
    const float* __restrict__ x, const float* __restrict__ y,
    const float* __restrict__ tw, const float* __restrict__ tb,
    const float* __restrict__ pw, const float* __restrict__ pb,
    const float* __restrict__ gw, const float* __restrict__ gb,
    _Float16* __restrict__ th16, _Float16* __restrict__ ph16,
    _Float16* __restrict__ g16) {
  const int ptile = blockIdx.x;   // 16 tiles of 256 positions
  const int og = blockIdx.y;      // 8 groups of 16 out-channels
  const int z = blockIdx.z;       // 12 = 3 proj * 4 batch
  const int pr = z >> 2, n = z & 3;
  const float* src = (pr == 1) ? y : x;
  const float* w = (pr == 0) ? tw : (pr == 1 ? pw : gw);
  const float* bp = (pr == 0) ? tb : (pr == 1 ? pb : gb);
  const int o0 = og * 16;
  __shared__ float wl[256][16];   // [c][o] transposed
  for (int e = threadIdx.x; e < 4096; e += 256) {
    int c = e & 255, o = e >> 8;
    wl[c][o] = w[(size_t)(o0 + o) * 256 + c];
  }
  __syncthreads();
  const int p = ptile * 256 + threadIdx.x;
  const float* sp = src + (size_t)n * C_DIM * HW_DIM + p;
  f32x4 a0 = {0.f, 0.f, 0.f, 0.f}, a1 = a0, a2 = a0, a3 = a0;
#pragma unroll 4
  for (int c = 0; c < 256; ++c) {
    float xv = sp[(size_t)c * HW_DIM];
    const f32x4* wr = (const f32x4*)wl[c];   // uniform -> LDS broadcast
    a0 += wr[0] * xv;
    a1 += wr[1] * xv;
    a2 += wr[2] * xv;
    a3 += wr[3] * xv;
  }
  float acc[16];
#pragma unroll
  for (int j = 0; j < 4; ++j) {
    acc[j] = a0[j]; acc[4 + j] = a1[j]; acc[8 + j] = a2[j]; acc[12 + j] = a3[j];
  }
  if (pr < 2) {
    _Float16* dst = (pr == 0 ? th16 : ph16) + ((size_t)n * HW_DIM + p) * CI_DIM + o0;
    f16x8 h0, h1;
#pragma unroll
    for (int j = 0; j < 8; ++j) {
      h0[j] = (_Float16)(acc[j] + bp[o0 + j]);
      h1[j] = (_Float16)(acc[8 + j] + bp[o0 + 8 + j]);
    }
    *(f16x8*)dst = h0;
    *(f16x8*)(dst + 8) = h1;
  } else {
#pragma unroll
    for (int o = 0; o < 16; ++o)
      g16[((size_t)n * CI_DIM + o0 + o) * HW_DIM + p] = (_Float16)(acc[o] + bp[o0 + o]);
  }
}

// ---------------- flash attention: 8 waves = 4 q-sub x 2 k-half, split-K merge
__global__ __launch_bounds__(512) void attn_kernel(
    const _Float16* __restrict__ th16, const _Float16* __restrict__ ph16,
    const _Float16* __restrict__ g16, _Float16* __restrict__ o16) {
  const int lin = blockIdx.x;  // 256 blocks
  const int xcd = lin & 7;     // 2 XCDs per batch -> phi/g L2-resident
  const int n = xcd >> 1;
  const int qt = ((lin >> 3) << 1) | (xcd & 1);
  const int q0 = qt * 64;
  const int tid = threadIdx.x;
  const int wv = tid >> 6, lane = tid & 63, lg = lane >> 4, lr = lane & 15;
  const int half = wv & 1, qsub = wv >> 1;

  // K bufs 64KB + G bufs 64KB + P 16KB = 144KB
  __shared__ __align__(16) char smem[147456];
#define KBUF(h, b) (smem + ((h)*2 + (b)) * 16384)
#define GBUF(h, b) (smem + 65536 + ((h)*2 + (b)) * 16384)
  char* pB = smem + 131072 + wv * 2048;

  const char* thn = (const char*)(th16 + (size_t)n * HW_DIM * CI_DIM);
  const char* phn = (const char*)(ph16 + (size_t)n * HW_DIM * CI_DIM);
  const char* ggn = (const char*)(g16 + (size_t)n * CI_DIM * HW_DIM);

  // pre-swizzled staging sources (linear LDS dest + inverse-swz source + swz reads)
  const char* ksrc = phn + (tid >> 4) * 256 + (((tid & 15) * 16) ^ (((tid >> 4) & 7) << 4));
  const char* gsrc = ggn + (size_t)(tid >> 3) * 8192 + (((tid & 7) * 16) ^ (((tid >> 3) & 7) << 4));

#define STAGE(KT, B)                                                                     \
  do {                                                                                   \
    _Pragma("unroll") for (int h_ = 0; h_ < 2; ++h_) {                                   \
      const char* ks = ksrc + (size_t)(h_ * 2048 + (KT) * 64) * 256;                     \
      const char* gs = gsrc + (size_t)(h_ * 2048 + (KT) * 64) * 2;                       \
      char* kd = KBUF(h_, B) + tid * 16;                                                 \
      char* gd = GBUF(h_, B) + tid * 16;                                                 \
      __builtin_amdgcn_global_load_lds((as1_u32*)ks, (as3_u32*)kd, 16, 0, 0);            \
      __builtin_amdgcn_global_load_lds((as1_u32*)(ks + 8192), (as3_u32*)(kd + 8192), 16, 0, 0); \
      __builtin_amdgcn_global_load_lds((as1_u32*)gs, (as3_u32*)gd, 16, 0, 0);            \
      __builtin_amdgcn_global_load_lds((as1_u32*)(gs + 524288), (as3_u32*)(gd + 8192), 16, 0, 0); \
    }                                                                                    \
  } while (0)

  // Q fragment: A[row=q=lr][k=ci], 16B contiguous from [pos][ci] layout
  f16x8 qf[4];
#pragma unroll
  for (int ch = 0; ch < 4; ++ch)
    qf[ch] = *(const f16x8*)(thn + (size_t)(q0 + qsub * 16 + lr) * 256 + ch * 64 + lg * 16);

  const int xorv = (lr & 7) << 4;
  int cbx[4];
#pragma unroll
  for (int ch = 0; ch < 4; ++ch) cbx[ch] = (ch * 64 + lg * 16) ^ xorv;

  f32x4 acc[8];
#pragma unroll
  for (int of = 0; of < 8; ++of) acc[of] = f32x4{0.f, 0.f, 0.f, 0.f};
  float mrow[4] = {-INFINITY, -INFINITY, -INFINITY, -INFINITY};
  float lrow[4] = {0.f, 0.f, 0.f, 0.f};

  STAGE(0, 0);
  __syncthreads();

  for (int kt = 0; kt < 32; ++kt) {
    const int b = kt & 1;
    if (kt < 31) STAGE(kt + 1, b ^ 1);

    // QK^T from this half's K buffer
    const char* kb = KBUF(half, b);
    f32x4 s[4];
#pragma unroll
    for (int cf = 0; cf < 4; ++cf) {
      const char* krow = kb + (cf * 16 + lr) * 256;
      f32x4 sv = f32x4{0.f, 0.f, 0.f, 0.f};
#pragma unroll
      for (int ch = 0; ch < 4; ++ch) {
        f16x8 kf = *(const f16x8*)(krow + cbx[ch]);
        sv = __builtin_amdgcn_mfma_f32_16x16x32_f16(qf[ch], kf, sv, 0, 0, 0);
      }
      s[cf] = sv;
    }

    // online softmax; S layout: row q = lg*4+r, col k = cf*16+lr
    float scfa[4];
#pragma unroll
    for (int r = 0; r < 4; ++r) {
      float v0 = s[0][r], v1 = s[1][r], v2 = s[2][r], v3 = s[3][r];
      float mx = fmaxf(fmaxf(v0, v1), fmaxf(v2, v3));
      mx = fmaxf(mx, __shfl_xor(mx, 1));
      mx = fmaxf(mx, __shfl_xor(mx, 2));
      mx = fmaxf(mx, __shfl_xor(mx, 4));
      mx = fmaxf(mx, __shfl_xor(mx, 8));
      float mnew = fmaxf(mrow[r], mx);
      float sc = __expf(mrow[r] - mnew);
      float p0 = __expf(v0 - mnew);
      float p1 = __expf(v1 - mnew);
      float p2 = __expf(v2 - mnew);
      float p3 = __expf(v3 - mnew);
      float sm = p0 + p1 + p2 + p3;
      sm += __shfl_xor(sm, 1);
      sm += __shfl_xor(sm, 2);
      sm += __shfl_xor(sm, 4);
      sm += __shfl_xor(sm, 8);
      lrow[r] = lrow[r] * sc + sm;
      mrow[r] = mnew;
      scfa[r] = sc;
      const int rl = lg * 4 + r;
      const int xp = (rl & 7) << 4;
      char* prow = pB + rl * 128;
      *(_Float16*)(prow + ((lr * 2) ^ xp)) = (_Float16)p0;
      *(_Float16*)(prow + ((32 + lr * 2) ^ xp)) = (_Float16)p1;
      *(_Float16*)(prow + ((64 + lr * 2) ^ xp)) = (_Float16)p2;
      *(_Float16*)(prow + ((96 + lr * 2) ^ xp)) = (_Float16)p3;
    }
    // rescale O^T (col = q = lr): broadcast per-q factor
    float sel = (lr & 2) ? ((lr & 1) ? scfa[3] : scfa[2]) : ((lr & 1) ? scfa[1] : scfa[0]);
    float scq = __shfl(sel, ((lr >> 2) << 4) | (lr & 3));
#pragma unroll
    for (int of = 0; of < 8; ++of) acc[of] *= scq;

    // PV: O^T = G * P^T
    const char* gb = GBUF(half, b);
#pragma unroll
    for (int kc = 0; kc < 2; ++kc) {
      f16x8 pf = *(const f16x8*)(pB + lr * 128 + cbx[kc]);
#pragma unroll
      for (int of = 0; of < 8; ++of) {
        f16x8 gf = *(const f16x8*)(gb + (of * 16 + lr) * 128 + cbx[kc]);
        acc[of] = __builtin_amdgcn_mfma_f32_16x16x32_f16(gf, pf, acc[of], 0, 0, 0);
      }
    }
    __syncthreads();  // drains stage(kt+1); all waves done reading buf b
  }

  // ----- split-K merge: per-lane (q = lr) state
  float msel = (lr & 2) ? ((lr & 1) ? mrow[3] : mrow[2]) : ((lr & 1) ? mrow[1] : mrow[0]);
  float mq = __shfl(msel, ((lr >> 2) << 4) | (lr & 3));
  float lsel = (lr & 2) ? ((lr & 1) ? lrow[3] : lrow[2]) : ((lr & 1) ? lrow[1] : lrow[0]);
  float lq = __shfl(lsel, ((lr >> 2) << 4) | (lr & 3));

  float* mg = (float*)(smem + qsub * 9216);  // 64 lanes x 36 f32
  if (half == 1) {
#pragma unroll
    for (int of = 0; of < 8; ++of)
#pragma unroll
      for (int r = 0; r < 4; ++r) mg[lane * 36 + of * 4 + r] = acc[of][r];
    mg[lane * 36 + 32] = mq;
    mg[lane * 36 + 33] = lq;
  }
  __syncthreads();
  if (half == 0) {
    float pm = mg[lane * 36 + 32];
    float pl = mg[lane * 36 + 33];
    float mm = fmaxf(mq, pm);
    float a0 = __expf(mq - mm), a1 = __expf(pm - mm);
    float inv = 1.0f / (lq * a0 + pl * a1);
#pragma unroll
    for (int of = 0; of < 8; ++of)
#pragma unroll
      for (int r = 0; r < 4; ++r)
        acc[of][r] = (acc[of][r] * a0 + mg[lane * 36 + of * 4 + r] * a1) * inv;
  }
  __syncthreads();
  if (half == 0) {
    // transpose O^T -> [q][ci] through LDS, store fp16 coalesced
    float* ep = (float*)(smem + qsub * 8448);  // 16 rows x 132 f32
#pragma unroll
    for (int of = 0; of < 8; ++of)
#pragma unroll
      for (int r = 0; r < 4; ++r) ep[lr * 132 + of * 16 + lg * 4 + r] = acc[of][r];
    char* on = (char*)(o16 + (size_t)n * HW_DIM * CI_DIM);
#pragma unroll
    for (int it = 0; it < 4; ++it) {
      int e = lane + it * 64;
      int q = e >> 4, c8 = e & 15;
      f32x4 va = *(const f32x4*)(ep + q * 132 + c8 * 8);
      f32x4 vb = *(const f32x4*)(ep + q * 132 + c8 * 8 + 4);
      f16x8 h;
#pragma unroll
      for (int j = 0; j < 4; ++j) { h[j] = (_Float16)va[j]; h[4 + j] = (_Float16)vb[j]; }
      *(f16x8*)(on + (size_t)(q0 + qsub * 16 + q) * 256 + c8 * 16) = h;
    }
  }
#undef STAGE
#undef KBUF
#undef GBUF
}

// ---------------- rec projection (MFMA) + BN partial stats
__global__ __launch_bounds__(256) void rec_kernel(
    const _Float16* __restrict__ o16, const float* __restrict__ rw,
    const float* __restrict__ rb, float* __restrict__ out,
    float* __restrict__ stats) {
  const int pblk = blockIdx.x;  // 128 tiles of 32 positions
  const int n = blockIdx.y;
  const int p0 = pblk * 32;
  const int tid = threadIdx.x, wv = tid >> 6, lane = tid & 63, lg = lane >> 4, lr = lane & 15;
  __shared__ __align__(16) char sB[8192];  // O tile [32 pos][128 ci] fp16, swizzled
  const char* o16n = (const char*)(o16 + (size_t)n * HW_DIM * CI_DIM);
  const char* srcb = o16n + (size_t)p0 * 256 + (tid >> 4) * 256 +
                     (((tid & 15) * 16) ^ (((tid >> 4) & 7) << 4));
  __builtin_amdgcn_global_load_lds((as1_u32*)srcb, (as3_u32*)(sB + tid * 16), 16, 0, 0);
  __builtin_amdgcn_global_load_lds((as1_u32*)(srcb + 4096), (as3_u32*)(sB + 4096 + tid * 16), 16, 0, 0);

  const int wc0 = wv * 64;  // wave owns 64 out-channels
  f16x8 a[4][4];            // A = W_rec fragments [mf][kc]
#pragma unroll
  for (int mf = 0; mf < 4; ++mf)
#pragma unroll
    for (int kc = 0; kc < 4; ++kc)
#pragma unroll
      for (int j = 0; j < 8; ++j)
        a[mf][kc][j] = (_Float16)rw[(size_t)(wc0 + mf * 16 + lr) * 128 + kc * 32 + lg * 8 + j];
  __syncthreads();

  f32x4 acc[4][2];
#pragma unroll
  for (int mf = 0; mf < 4; ++mf) {
    acc[mf][0] = f32x4{0.f, 0.f, 0.f, 0.f};
    acc[mf][1] = f32x4{0.f, 0.f, 0.f, 0.f};
  }
  const int xorv = (lr & 7) << 4;
#pragma unroll
  for (int kc = 0; kc < 4; ++kc) {
    int cb = (kc * 64 + lg * 16) ^ xorv;
    f16x8 b0 = *(const f16x8*)(sB + lr * 256 + cb);
    f16x8 b1 = *(const f16x8*)(sB + (16 + lr) * 256 + cb);
#pragma unroll
    for (int mf = 0; mf < 4; ++mf) {
      acc[mf][0] = __builtin_amdgcn_mfma_f32_16x16x32_f16(a[mf][kc], b0, acc[mf][0], 0, 0, 0);
      acc[mf][1] = __builtin_amdgcn_mfma_f32_16x16x32_f16(a[mf][kc], b1, acc[mf][1], 0, 0, 0);
    }
  }
  // D[row=c=wc0+mf*16+lg*4+r][col=p=p0+nf*16+lr]
#pragma unroll
  for (int mf = 0; mf < 4; ++mf)
#pragma unroll
    for (int r = 0; r < 4; ++r) {
      int c = wc0 + mf * 16 + lg * 4 + r;
      float bias = rb[c];
      float v0 = acc[mf][0][r] + bias;
      float v1 = acc[mf][1][r] + bias;
      out[((size_t)n * C_DIM + c) * HW_DIM + p0 + lr] = v0;
      out[((size_t)n * C_DIM + c) * HW_DIM + p0 + 16 + lr] = v1;
      float s = v0 + v1, q = v0 * v0 + v1 * v1;
      s += __shfl_xor(s, 1); q += __shfl_xor(q, 1);
      s += __shfl_xor(s, 2); q += __shfl_xor(q, 2);
      s += __shfl_xor(s, 4); q += __shfl_xor(q, 4);
      s += __shfl_xor(s, 8); q += __shfl_xor(q, 8);
      if (lr == 0) {
        atomicAdd(&stats[c], s);
        atomicAdd(&stats[C_DIM + c], q);
      }
    }
}

// ---------------- BN apply + residual, in place on d_out
__global__ __launch_bounds__(256) void bn_kernel(
    const float* __restrict__ x, const float* __restrict__ gamma,
    const float* __restrict__ beta, const float* __restrict__ stats,
    float* __restrict__ out) {
  const size_t i4 = (size_t)blockIdx.x * 256 + threadIdx.x;
  const int c = (int)((i4 >> 10) & 255);
  const float inv = 1.f / 16384.f;
  const float mean = stats[c] * inv;
  const float var = stats[C_DIM + c] * inv - mean * mean;
  const float gm = gamma[c] * rsqrtf(var + EPSV);
  const float bt = beta[c];
  float4 rv = ((const float4*)out)[i4];
  float4 xv = ((const float4*)x)[i4];
  float4 o;
  o.x = xv.x + (rv.x - mean) * gm + bt;
  o.y = xv.y + (rv.y - mean) * gm + bt;
  o.z = xv.z + (rv.z - mean) * gm + bt;
  o.w = xv.w + (rv.w - mean) * gm + bt;
  ((float4*)out)[i4] = o;
}

extern "C" void kernel_launch(void* const* d_in, const int* in_sizes, int n_in,
                              void* d_out, int out_size, void* d_ws, size_t ws_size,
                              hipStream_t stream) {
  const float* x  = (const float*)d_in[0];
  const float* y  = (const float*)d_in[1];
  const float* tw = (const float*)d_in[2];
  const float* tb = (const float*)d_in[3];
  const float* pw = (const float*)d_in[4];
  const float* pb = (const float*)d_in[5];
  const float* gw = (const float*)d_in[6];
  const float* gb = (const float*)d_in[7];
  const float* rw = (const float*)d_in[8];
  const float* rb = (const float*)d_in[9];
  const float* gamma = (const float*)d_in[10];
  const float* beta  = (const float*)d_in[11];
  float* out = (float*)d_out;
  _Float16* th16 = (_Float16*)d_ws;                  // 4MB [n][pos][ci]
  _Float16* ph16 = th16 + 2097152;                   // 4MB [n][pos][ci]
  _Float16* g16  = ph16 + 2097152;                   // 4MB [n][ci][pos]
  _Float16* o16  = g16 + 2097152;                    // 4MB [n][q][ci]
  float* stats = (float*)(o16 + 2097152);            // 512 f32
  hipMemsetAsync(stats, 0, 2 * C_DIM * sizeof(float), stream);
  proj_kernel<<<dim3(16, 8, 12), 256, 0, stream>>>(x, y, tw, tb, pw, pb, gw, gb,
                                                   th16, ph16, g16);
  attn_kernel<<<dim3(256), 512, 0, stream>>>(th16, ph16, g16, o16);
  rec_kernel<<<dim3(128, 4), 256, 0, stream>>>(o16, rw, rb, out, stats);
  bn_kernel<<<dim3(4096), 256, 0, stream>>>(x, gamma, beta, stats, out);
}

// Round 5
// 190.406 us; speedup vs baseline: 3.3495x; 1.2919x over previous
//
#include <hip/hip_runtime.h>
#include <math.h>

#define EPSV 1e-5f

typedef __attribute__((ext_vector_type(8))) _Float16 f16x8;
typedef __attribute__((ext_vector_type(4))) float f32x4;

typedef __attribute__((address_space(1))) const unsigned int as1_u32;
typedef __attribute__((address_space(3))) unsigned int as3_u32;

static __device__ __forceinline__ unsigned packh2(float a, float b) {
  auto v = __builtin_amdgcn_cvt_pkrtz(a, b);  // __fp16 ext_vector(2)
  return __builtin_bit_cast(unsigned, v);
}

// ---------------- pack weights fp32 -> fp16 [3][128][256]
__global__ __launch_bounds__(256) void pack_w(const float* __restrict__ tw,
                                              const float* __restrict__ pw,
                                              const float* __restrict__ gw,
                                              _Float16* __restrict__ w16) {
  int i = blockIdx.x * 256 + threadIdx.x;  // 98304
  const float* s = i < 32768 ? tw : (i < 65536 ? pw : gw);
  w16[i] = (_Float16)s[i & 32767];
}

// ---------------- pack x,y fp32 [n][c][p] -> fp16 transposed [src][n][p][c]
__global__ __launch_bounds__(256) void pack_xy(const float* __restrict__ x,
                                               const float* __restrict__ y,
                                               _Float16* __restrict__ xt) {
  const int n = blockIdx.y, s = blockIdx.z;
  const int g = blockIdx.x * 256 + threadIdx.x;  // 131072 per (n,s)
  const int p = g & 4095, c8 = g >> 12;          // c8 0..31
  const float* src = (s ? y : x) + ((size_t)n * 256 + c8 * 8) * 4096 + p;
  f16x8 v;
#pragma unroll
  for (int j = 0; j < 8; ++j) v[j] = (_Float16)src[(size_t)j * 4096];
  *(f16x8*)(xt + ((size_t)(s * 4 + n) * 4096 + p) * 256 + c8 * 8) = v;
}

// ---------------- projections via MFMA.
// pr 0 (theta): D=W*X -> [ci][p]; pr 1 (phi): D=X^T*W^T -> [p][ci]; pr 2 (g): D=W*X -> [ci][p]
__global__ __launch_bounds__(256) void proj_kernel(
    const _Float16* __restrict__ xt, const _Float16* __restrict__ w16,
    const float* __restrict__ tb, const float* __restrict__ pb,
    const float* __restrict__ gb, _Float16* __restrict__ th16,
    _Float16* __restrict__ ph16, _Float16* __restrict__ g16) {
  const int ptile = blockIdx.x;  // 32 tiles of 128 positions
  const int z = blockIdx.y;      // 12 = 3 pr * 4 n
  const int pr = z >> 2, n = z & 3;
  const int p0 = ptile * 128;
  const int tid = threadIdx.x, wv = tid >> 6, lane = tid & 63, lg = lane >> 4, lr = lane & 15;

  __shared__ __align__(16) char sB[65536];  // X tile [128 p][256 c] fp16, swz ((p&7)<<4)

  const int srcn = (pr == 1 ? 4 : 0) + n;
  const char* src = (const char*)(xt + ((size_t)srcn * 4096 + p0) * 256);
#pragma unroll
  for (int ps = 0; ps < 16; ++ps) {
    int L = ps * 4096 + tid * 16;
    int row = L >> 9, col = L & 511;
    __builtin_amdgcn_global_load_lds((as1_u32*)(src + (size_t)row * 512 + (col ^ ((row & 7) << 4))),
                                     (as3_u32*)(sB + L), 16, 0, 0);
  }
  const _Float16* wp = w16 + pr * 32768;
  const float* bp = pr == 0 ? tb : (pr == 1 ? pb : gb);

  if (pr != 1) {
    const int o0 = wv * 32;
    f16x8 a[2][8];
#pragma unroll
    for (int mf = 0; mf < 2; ++mf)
#pragma unroll
      for (int kc = 0; kc < 8; ++kc)
        a[mf][kc] = *(const f16x8*)(wp + (size_t)(o0 + mf * 16 + lr) * 256 + kc * 32 + lg * 8);
    __syncthreads();
    f32x4 acc[2][8];
#pragma unroll
    for (int mf = 0; mf < 2; ++mf)
#pragma unroll
      for (int nf = 0; nf < 8; ++nf) acc[mf][nf] = f32x4{0.f, 0.f, 0.f, 0.f};
#pragma unroll
    for (int kc = 0; kc < 8; ++kc) {
      f16x8 bf[8];
#pragma unroll
      for (int nf = 0; nf < 8; ++nf)
        bf[nf] = *(const f16x8*)(sB + (nf * 16 + lr) * 512 + ((kc * 64 + lg * 16) ^ ((lr & 7) << 4)));
#pragma unroll
      for (int mf = 0; mf < 2; ++mf)
#pragma unroll
        for (int nf = 0; nf < 8; ++nf)
          acc[mf][nf] = __builtin_amdgcn_mfma_f32_16x16x32_f16(a[mf][kc], bf[nf], acc[mf][nf], 0, 0, 0);
    }
    _Float16* out = (pr == 0 ? th16 : g16) + (size_t)n * 128 * 4096;
#pragma unroll
    for (int mf = 0; mf < 2; ++mf)
#pragma unroll
      for (int r = 0; r < 4; ++r) {
        int o = o0 + mf * 16 + lg * 4 + r;
        float bias = bp[o];
#pragma unroll
        for (int nf = 0; nf < 8; ++nf)
          out[(size_t)o * 4096 + p0 + nf * 16 + lr] = (_Float16)(acc[mf][nf][r] + bias);
      }
  } else {
    __syncthreads();
    const int pw0 = wv * 32;
    f32x4 acc[2][8];
#pragma unroll
    for (int mf = 0; mf < 2; ++mf)
#pragma unroll
      for (int nf = 0; nf < 8; ++nf) acc[mf][nf] = f32x4{0.f, 0.f, 0.f, 0.f};
#pragma unroll 2
    for (int kc = 0; kc < 8; ++kc) {
      f16x8 bf[8];
#pragma unroll
      for (int nf = 0; nf < 8; ++nf)
        bf[nf] = *(const f16x8*)(wp + (size_t)(nf * 16 + lr) * 256 + kc * 32 + lg * 8);
      f16x8 af[2];
#pragma unroll
      for (int mf = 0; mf < 2; ++mf)
        af[mf] = *(const f16x8*)(sB + (pw0 + mf * 16 + lr) * 512 + ((kc * 64 + lg * 16) ^ ((lr & 7) << 4)));
#pragma unroll
      for (int mf = 0; mf < 2; ++mf)
#pragma unroll
        for (int nf = 0; nf < 8; ++nf)
          acc[mf][nf] = __builtin_amdgcn_mfma_f32_16x16x32_f16(af[mf], bf[nf], acc[mf][nf], 0, 0, 0);
    }
    _Float16* out = ph16 + (size_t)n * 4096 * 128;
#pragma unroll
    for (int mf = 0; mf < 2; ++mf)
#pragma unroll
      for (int r = 0; r < 4; ++r) {
        int p = p0 + pw0 + mf * 16 + lg * 4 + r;
#pragma unroll
        for (int nf = 0; nf < 8; ++nf) {
          int o = nf * 16 + lr;
          out[(size_t)p * 128 + o] = (_Float16)(acc[mf][nf][r] + bp[o]);
        }
      }
  }
}

// ---------------- flash attention: swapped QK^T (lane owns one q), split-K x2
__global__ __launch_bounds__(512) void attn_kernel(
    const _Float16* __restrict__ th16, const _Float16* __restrict__ ph16,
    const _Float16* __restrict__ g16, _Float16* __restrict__ o16) {
  const int lin = blockIdx.x;  // 256
  const int xcd = lin & 7;     // 2 XCDs per batch
  const int n = xcd >> 1;
  const int qt = ((lin >> 3) << 1) | (xcd & 1);
  const int q0 = qt * 64;
  const int tid = threadIdx.x;
  const int wv = tid >> 6, lane = tid & 63, lg = lane >> 4, lr = lane & 15;
  const int half = wv & 1, qsub = wv >> 1;

  // K 4x16KB + G 4x16KB + P 8x2KB = 144KB
  __shared__ __align__(16) char smem[147456];
#define KBUF(h, b) (smem + ((h)*2 + (b)) * 16384)
#define GBUF(h, b) (smem + 65536 + ((h)*2 + (b)) * 16384)
  char* pB = smem + 131072 + wv * 2048;

  const _Float16* thn = th16 + (size_t)n * 128 * 4096;
  const char* phn = (const char*)(ph16 + (size_t)n * 4096 * 128);
  const char* ggn = (const char*)(g16 + (size_t)n * 128 * 4096);

  const char* ksrc = phn + (tid >> 4) * 256 + (((tid & 15) * 16) ^ (((tid >> 4) & 7) << 4));
  const char* gsrc = ggn + (size_t)(tid >> 3) * 8192 + (((tid & 7) * 16) ^ (((tid >> 3) & 7) << 4));

#define STAGE(KT, B)                                                                     \
  do {                                                                                   \
    _Pragma("unroll") for (int h_ = 0; h_ < 2; ++h_) {                                   \
      const char* ks = ksrc + (size_t)(h_ * 2048 + (KT) * 64) * 256;                     \
      const char* gs = gsrc + (size_t)(h_ * 2048 + (KT) * 64) * 2;                       \
      char* kd = KBUF(h_, B) + tid * 16;                                                 \
      char* gd = GBUF(h_, B) + tid * 16;                                                 \
      __builtin_amdgcn_global_load_lds((as1_u32*)ks, (as3_u32*)kd, 16, 0, 0);            \
      __builtin_amdgcn_global_load_lds((as1_u32*)(ks + 8192), (as3_u32*)(kd + 8192), 16, 0, 0); \
      __builtin_amdgcn_global_load_lds((as1_u32*)gs, (as3_u32*)gd, 16, 0, 0);            \
      __builtin_amdgcn_global_load_lds((as1_u32*)(gs + 524288), (as3_u32*)(gd + 8192), 16, 0, 0); \
    }                                                                                    \
  } while (0)

  // Q fragment (B-operand): B[k=ci][n=q=lr], content Q[q=lr][ci=ch*32+lg*8+j]
  const int q = q0 + qsub * 16 + lr;
  f16x8 qf[4];
#pragma unroll
  for (int ch = 0; ch < 4; ++ch)
#pragma unroll
    for (int j = 0; j < 8; ++j)
      qf[ch][j] = thn[(size_t)(ch * 32 + lg * 8 + j) * 4096 + q];

  const int swzk = (lr & 7) << 4;
  const int swzp = (lr & 15) << 3;

  f32x4 acc[8];
#pragma unroll
  for (int of = 0; of < 8; ++of) acc[of] = f32x4{0.f, 0.f, 0.f, 0.f};
  float mrow = -INFINITY, lrow = 0.f;

  STAGE(0, 0);
  __syncthreads();

  for (int kt = 0; kt < 32; ++kt) {
    const int b = kt & 1;
    if (kt < 31) STAGE(kt + 1, b ^ 1);

    // S^T = K * Q^T : D[k=cf*16+lg*4+r][q=lr]
    const char* kb = KBUF(half, b);
    f32x4 s[4];
    __builtin_amdgcn_s_setprio(1);
#pragma unroll
    for (int cf = 0; cf < 4; ++cf) {
      const char* krow = kb + (cf * 16 + lr) * 256;
      f32x4 sv = f32x4{0.f, 0.f, 0.f, 0.f};
#pragma unroll
      for (int ch = 0; ch < 4; ++ch) {
        f16x8 kf = *(const f16x8*)(krow + ((ch * 64 + lg * 16) ^ swzk));
        sv = __builtin_amdgcn_mfma_f32_16x16x32_f16(kf, qf[ch], sv, 0, 0, 0);
      }
      s[cf] = sv;
    }
    __builtin_amdgcn_s_setprio(0);

    // online softmax, lane-local q
    float mt = s[0][0];
#pragma unroll
    for (int cf = 0; cf < 4; ++cf)
#pragma unroll
      for (int r = 0; r < 4; ++r) mt = fmaxf(mt, s[cf][r]);
    mt = fmaxf(mt, __shfl_xor(mt, 16));
    mt = fmaxf(mt, __shfl_xor(mt, 32));
    if (!__all(mt <= mrow + 8.0f)) {  // defer-max (THR=8)
      float mnew = fmaxf(mrow, mt);
      float sc = __expf(mrow - mnew);
#pragma unroll
      for (int of = 0; of < 8; ++of) acc[of] *= sc;
      lrow *= sc;
      mrow = mnew;
    }
    float psum = 0.f;
    char* prow = pB + lr * 128;
#pragma unroll
    for (int cf = 0; cf < 4; ++cf) {
      float p0 = __expf(s[cf][0] - mrow);
      float p1 = __expf(s[cf][1] - mrow);
      float p2 = __expf(s[cf][2] - mrow);
      float p3 = __expf(s[cf][3] - mrow);
      psum += (p0 + p1) + (p2 + p3);
      unsigned long long w = (unsigned long long)packh2(p0, p1) |
                             ((unsigned long long)packh2(p2, p3) << 32);
      *(unsigned long long*)(prow + ((cf * 32 + lg * 8) ^ swzp)) = w;
    }
    psum += __shfl_xor(psum, 16);
    psum += __shfl_xor(psum, 32);
    lrow += psum;

    // PV: O^T = G * P^T ; D[ci=of*16+lg*4+r][q=lr]
    const char* gb = GBUF(half, b);
    __builtin_amdgcn_s_setprio(1);
#pragma unroll
    for (int kc = 0; kc < 2; ++kc) {
      int b0 = kc * 64 + lg * 16;
      unsigned long long w0 = *(const unsigned long long*)(prow + (b0 ^ swzp));
      unsigned long long w1 = *(const unsigned long long*)(prow + ((b0 + 8) ^ swzp));
      f16x8 pf;
      unsigned* pu = (unsigned*)&pf;
      pu[0] = (unsigned)w0; pu[1] = (unsigned)(w0 >> 32);
      pu[2] = (unsigned)w1; pu[3] = (unsigned)(w1 >> 32);
#pragma unroll
      for (int of = 0; of < 8; ++of) {
        f16x8 gf = *(const f16x8*)(gb + (of * 16 + lr) * 128 + ((kc * 64 + lg * 16) ^ swzk));
        acc[of] = __builtin_amdgcn_mfma_f32_16x16x32_f16(gf, pf, acc[of], 0, 0, 0);
      }
    }
    __builtin_amdgcn_s_setprio(0);
    __syncthreads();  // drains stage(kt+1); all waves done with buf b
  }

  // ----- split-K merge (per-lane scalars: q = lr)
  float* mg = (float*)(smem + qsub * 9216);  // 64 lanes x 36 f32
  if (half == 1) {
#pragma unroll
    for (int of = 0; of < 8; ++of)
#pragma unroll
      for (int r = 0; r < 4; ++r) mg[lane * 36 + of * 4 + r] = acc[of][r];
    mg[lane * 36 + 32] = mrow;
    mg[lane * 36 + 33] = lrow;
  }
  __syncthreads();
  if (half == 0) {
    float pm = mg[lane * 36 + 32];
    float pl = mg[lane * 36 + 33];
    float mm = fmaxf(mrow, pm);
    float a0 = __expf(mrow - mm), a1 = __expf(pm - mm);
    float inv = 1.0f / (lrow * a0 + pl * a1);
#pragma unroll
    for (int of = 0; of < 8; ++of)
#pragma unroll
      for (int r = 0; r < 4; ++r)
        acc[of][r] = (acc[of][r] * a0 + mg[lane * 36 + of * 4 + r] * a1) * inv;
  }
  __syncthreads();
  if (half == 0) {
    // transpose O^T -> [q][ci] through LDS, store fp16 coalesced
    float* ep = (float*)(smem + qsub * 8448);  // 16 rows x 132 f32
#pragma unroll
    for (int of = 0; of < 8; ++of)
#pragma unroll
      for (int r = 0; r < 4; ++r) ep[lr * 132 + of * 16 + lg * 4 + r] = acc[of][r];
    char* on = (char*)(o16 + (size_t)n * 4096 * 128);
#pragma unroll
    for (int it = 0; it < 4; ++it) {
      int e = lane + it * 64;
      int qq = e >> 4, c8 = e & 15;
      f32x4 va = *(const f32x4*)(ep + qq * 132 + c8 * 8);
      f32x4 vb = *(const f32x4*)(ep + qq * 132 + c8 * 8 + 4);
      f16x8 h;
#pragma unroll
      for (int j = 0; j < 4; ++j) { h[j] = (_Float16)va[j]; h[4 + j] = (_Float16)vb[j]; }
      *(f16x8*)(on + (size_t)(q0 + qsub * 16 + qq) * 256 + c8 * 16) = h;
    }
  }
#undef STAGE
#undef KBUF
#undef GBUF
}

// ---------------- rec projection (MFMA) + BN partial stats
__global__ __launch_bounds__(256) void rec_kernel(
    const _Float16* __restrict__ o16, const float* __restrict__ rw,
    const float* __restrict__ rb, float* __restrict__ out,
    float* __restrict__ stats) {
  const int pblk = blockIdx.x;  // 128 tiles of 32 positions
  const int n = blockIdx.y;
  const int p0 = pblk * 32;
  const int tid = threadIdx.x, wv = tid >> 6, lane = tid & 63, lg = lane >> 4, lr = lane & 15;
  __shared__ __align__(16) char sB[8192];  // O tile [32 pos][128 ci] fp16, swizzled
  const char* o16n = (const char*)(o16 + (size_t)n * 4096 * 128);
  const char* srcb = o16n + (size_t)p0 * 256 + (tid >> 4) * 256 +
                     (((tid & 15) * 16) ^ (((tid >> 4) & 7) << 4));
  __builtin_amdgcn_global_load_lds((as1_u32*)srcb, (as3_u32*)(sB + tid * 16), 16, 0, 0);
  __builtin_amdgcn_global_load_lds((as1_u32*)(srcb + 4096), (as3_u32*)(sB + 4096 + tid * 16), 16, 0, 0);

  const int wc0 = wv * 64;
  f16x8 a[4][4];
#pragma unroll
  for (int mf = 0; mf < 4; ++mf)
#pragma unroll
    for (int kc = 0; kc < 4; ++kc)
#pragma unroll
      for (int j = 0; j < 8; ++j)
        a[mf][kc][j] = (_Float16)rw[(size_t)(wc0 + mf * 16 + lr) * 128 + kc * 32 + lg * 8 + j];
  __syncthreads();

  f32x4 acc[4][2];
#pragma unroll
  for (int mf = 0; mf < 4; ++mf) {
    acc[mf][0] = f32x4{0.f, 0.f, 0.f, 0.f};
    acc[mf][1] = f32x4{0.f, 0.f, 0.f, 0.f};
  }
  const int xorv = (lr & 7) << 4;
#pragma unroll
  for (int kc = 0; kc < 4; ++kc) {
    int cb = (kc * 64 + lg * 16) ^ xorv;
    f16x8 b0 = *(const f16x8*)(sB + lr * 256 + cb);
    f16x8 b1 = *(const f16x8*)(sB + (16 + lr) * 256 + cb);
#pragma unroll
    for (int mf = 0; mf < 4; ++mf) {
      acc[mf][0] = __builtin_amdgcn_mfma_f32_16x16x32_f16(a[mf][kc], b0, acc[mf][0], 0, 0, 0);
      acc[mf][1] = __builtin_amdgcn_mfma_f32_16x16x32_f16(a[mf][kc], b1, acc[mf][1], 0, 0, 0);
    }
  }
#pragma unroll
  for (int mf = 0; mf < 4; ++mf)
#pragma unroll
    for (int r = 0; r < 4; ++r) {
      int c = wc0 + mf * 16 + lg * 4 + r;
      float bias = rb[c];
      float v0 = acc[mf][0][r] + bias;
      float v1 = acc[mf][1][r] + bias;
      out[((size_t)n * 256 + c) * 4096 + p0 + lr] = v0;
      out[((size_t)n * 256 + c) * 4096 + p0 + 16 + lr] = v1;
      float s = v0 + v1, qd = v0 * v0 + v1 * v1;
      s += __shfl_xor(s, 1); qd += __shfl_xor(qd, 1);
      s += __shfl_xor(s, 2); qd += __shfl_xor(qd, 2);
      s += __shfl_xor(s, 4); qd += __shfl_xor(qd, 4);
      s += __shfl_xor(s, 8); qd += __shfl_xor(qd, 8);
      if (lr == 0) {
        atomicAdd(&stats[c], s);
        atomicAdd(&stats[256 + c], qd);
      }
    }
}

// ---------------- BN apply + residual
__global__ __launch_bounds__(256) void bn_kernel(
    const float* __restrict__ x, const float* __restrict__ gamma,
    const float* __restrict__ beta, const float* __restrict__ stats,
    float* __restrict__ out) {
  const size_t i4 = (size_t)blockIdx.x * 256 + threadIdx.x;
  const int c = (int)((i4 >> 10) & 255);
  const float inv = 1.f / 16384.f;
  const float mean = stats[c] * inv;
  const float var = stats[256 + c] * inv - mean * mean;
  const float gm = gamma[c] * rsqrtf(var + EPSV);
  const float bt = beta[c];
  float4 rv = ((const float4*)out)[i4];
  float4 xv = ((const float4*)x)[i4];
  float4 o;
  o.x = xv.x + (rv.x - mean) * gm + bt;
  o.y = xv.y + (rv.y - mean) * gm + bt;
  o.z = xv.z + (rv.z - mean) * gm + bt;
  o.w = xv.w + (rv.w - mean) * gm + bt;
  ((float4*)out)[i4] = o;
}

extern "C" void kernel_launch(void* const* d_in, const int* in_sizes, int n_in,
                              void* d_out, int out_size, void* d_ws, size_t ws_size,
                              hipStream_t stream) {
  const float* x  = (const float*)d_in[0];
  const float* y  = (const float*)d_in[1];
  const float* tw = (const float*)d_in[2];
  const float* tb = (const float*)d_in[3];
  const float* pw = (const float*)d_in[4];
  const float* pb = (const float*)d_in[5];
  const float* gw = (const float*)d_in[6];
  const float* gb = (const float*)d_in[7];
  const float* rw = (const float*)d_in[8];
  const float* rb = (const float*)d_in[9];
  const float* gamma = (const float*)d_in[10];
  const float* beta  = (const float*)d_in[11];
  float* out = (float*)d_out;
  _Float16* xt   = (_Float16*)d_ws;        // 16MB [2][4][4096][256]
  _Float16* w16  = xt + 8388608;           // 192KB [3][128][256]
  _Float16* th16 = w16 + 98304;            // 4MB [n][ci][p]
  _Float16* ph16 = th16 + 2097152;         // 4MB [n][p][ci]
  _Float16* g16  = ph16 + 2097152;         // 4MB [n][ci][p]
  _Float16* o16  = g16 + 2097152;          // 4MB [n][q][ci]
  float* stats   = (float*)(o16 + 2097152);
  (void)hipMemsetAsync(stats, 0, 2 * 256 * sizeof(float), stream);
  pack_w<<<dim3(384), 256, 0, stream>>>(tw, pw, gw, w16);
  pack_xy<<<dim3(512, 4, 2), 256, 0, stream>>>(x, y, xt);
  proj_kernel<<<dim3(32, 12), 256, 0, stream>>>(xt, w16, tb, pb, gb, th16, ph16, g16);
  attn_kernel<<<dim3(256), 512, 0, stream>>>(th16, ph16, g16, o16);
  rec_kernel<<<dim3(128, 4), 256, 0, stream>>>(o16, rw, rb, out, stats);
  bn_kernel<<<dim3(4096), 256, 0, stream>>>(x, gamma, beta, stats, out);
}

// Round 6
// 139.628 us; speedup vs baseline: 4.5676x; 1.3637x over previous
//
#include <hip/hip_runtime.h>
#include <math.h>

#define EPSV 1e-5f

typedef __attribute__((ext_vector_type(8))) _Float16 f16x8;
typedef __attribute__((ext_vector_type(4))) float f32x4;

typedef __attribute__((address_space(1))) const unsigned int as1_u32;
typedef __attribute__((address_space(3))) unsigned int as3_u32;

static __device__ __forceinline__ unsigned packh2(float a, float b) {
  auto v = __builtin_amdgcn_cvt_pkrtz(a, b);  // __fp16 ext_vector(2)
  return __builtin_bit_cast(unsigned, v);
}

// ---------------- pack weights fp32 -> fp16 [4][*] (tw,pw,gw: 128x256; rw: 256x128)
__global__ __launch_bounds__(256) void pack_w(const float* __restrict__ tw,
                                              const float* __restrict__ pw,
                                              const float* __restrict__ gw,
                                              const float* __restrict__ rw,
                                              _Float16* __restrict__ w16) {
  int i = blockIdx.x * 256 + threadIdx.x;  // 131072
  const float* s = i < 32768 ? tw : (i < 65536 ? pw : (i < 98304 ? gw : rw));
  w16[i] = (_Float16)s[i & 32767];
}

// ---------------- pack x,y fp32 [n][c][p] -> fp16 transposed [src][n][p][c]
__global__ __launch_bounds__(256) void pack_xy(const float* __restrict__ x,
                                               const float* __restrict__ y,
                                               _Float16* __restrict__ xt) {
  const int n = blockIdx.y, s = blockIdx.z;
  const int g = blockIdx.x * 256 + threadIdx.x;  // 131072 per (n,s)
  const int p = g & 4095, c8 = g >> 12;          // c8 0..31
  const float* src = (s ? y : x) + ((size_t)n * 256 + c8 * 8) * 4096 + p;
  f16x8 v;
#pragma unroll
  for (int j = 0; j < 8; ++j) v[j] = (_Float16)src[(size_t)j * 4096];
  *(f16x8*)(xt + ((size_t)(s * 4 + n) * 4096 + p) * 256 + c8 * 8) = v;
}

// ---------------- projections via MFMA.
// pr 0 (theta): D=W*X -> [ci][p]; pr 1 (phi): D=X^T*W^T -> [p][ci]; pr 2 (g): D=W*X -> [ci][p]
__global__ __launch_bounds__(256) void proj_kernel(
    const _Float16* __restrict__ xt, const _Float16* __restrict__ w16,
    const float* __restrict__ tb, const float* __restrict__ pb,
    const float* __restrict__ gb, _Float16* __restrict__ th16,
    _Float16* __restrict__ ph16, _Float16* __restrict__ g16) {
  const int ptile = blockIdx.x;  // 32 tiles of 128 positions
  const int z = blockIdx.y;      // 12 = 3 pr * 4 n
  const int pr = z >> 2, n = z & 3;
  const int p0 = ptile * 128;
  const int tid = threadIdx.x, wv = tid >> 6, lane = tid & 63, lg = lane >> 4, lr = lane & 15;

  __shared__ __align__(16) char sB[65536];  // X tile [128 p][256 c] fp16, swz ((p&7)<<4)

  const int srcn = (pr == 1 ? 4 : 0) + n;
  const char* src = (const char*)(xt + ((size_t)srcn * 4096 + p0) * 256);
#pragma unroll
  for (int ps = 0; ps < 16; ++ps) {
    int L = ps * 4096 + tid * 16;
    int row = L >> 9, col = L & 511;
    __builtin_amdgcn_global_load_lds((as1_u32*)(src + (size_t)row * 512 + (col ^ ((row & 7) << 4))),
                                     (as3_u32*)(sB + L), 16, 0, 0);
  }
  const _Float16* wp = w16 + pr * 32768;
  const float* bp = pr == 0 ? tb : (pr == 1 ? pb : gb);

  if (pr != 1) {
    const int o0 = wv * 32;
    f16x8 a[2][8];
#pragma unroll
    for (int mf = 0; mf < 2; ++mf)
#pragma unroll
      for (int kc = 0; kc < 8; ++kc)
        a[mf][kc] = *(const f16x8*)(wp + (size_t)(o0 + mf * 16 + lr) * 256 + kc * 32 + lg * 8);
    __syncthreads();
    f32x4 acc[2][8];
#pragma unroll
    for (int mf = 0; mf < 2; ++mf)
#pragma unroll
      for (int nf = 0; nf < 8; ++nf) acc[mf][nf] = f32x4{0.f, 0.f, 0.f, 0.f};
#pragma unroll
    for (int kc = 0; kc < 8; ++kc) {
      f16x8 bf[8];
#pragma unroll
      for (int nf = 0; nf < 8; ++nf)
        bf[nf] = *(const f16x8*)(sB + (nf * 16 + lr) * 512 + ((kc * 64 + lg * 16) ^ ((lr & 7) << 4)));
#pragma unroll
      for (int mf = 0; mf < 2; ++mf)
#pragma unroll
        for (int nf = 0; nf < 8; ++nf)
          acc[mf][nf] = __builtin_amdgcn_mfma_f32_16x16x32_f16(a[mf][kc], bf[nf], acc[mf][nf], 0, 0, 0);
    }
    _Float16* out = (pr == 0 ? th16 : g16) + (size_t)n * 128 * 4096;
#pragma unroll
    for (int mf = 0; mf < 2; ++mf)
#pragma unroll
      for (int r = 0; r < 4; ++r) {
        int o = o0 + mf * 16 + lg * 4 + r;
        float bias = bp[o];
#pragma unroll
        for (int nf = 0; nf < 8; ++nf)
          out[(size_t)o * 4096 + p0 + nf * 16 + lr] = (_Float16)(acc[mf][nf][r] + bias);
      }
  } else {
    __syncthreads();
    const int pw0 = wv * 32;
    f32x4 acc[2][8];
#pragma unroll
    for (int mf = 0; mf < 2; ++mf)
#pragma unroll
      for (int nf = 0; nf < 8; ++nf) acc[mf][nf] = f32x4{0.f, 0.f, 0.f, 0.f};
#pragma unroll 2
    for (int kc = 0; kc < 8; ++kc) {
      f16x8 bf[8];
#pragma unroll
      for (int nf = 0; nf < 8; ++nf)
        bf[nf] = *(const f16x8*)(wp + (size_t)(nf * 16 + lr) * 256 + kc * 32 + lg * 8);
      f16x8 af[2];
#pragma unroll
      for (int mf = 0; mf < 2; ++mf)
        af[mf] = *(const f16x8*)(sB + (pw0 + mf * 16 + lr) * 512 + ((kc * 64 + lg * 16) ^ ((lr & 7) << 4)));
#pragma unroll
      for (int mf = 0; mf < 2; ++mf)
#pragma unroll
        for (int nf = 0; nf < 8; ++nf)
          acc[mf][nf] = __builtin_amdgcn_mfma_f32_16x16x32_f16(af[mf], bf[nf], acc[mf][nf], 0, 0, 0);
    }
    _Float16* out = ph16 + (size_t)n * 4096 * 128;
#pragma unroll
    for (int mf = 0; mf < 2; ++mf)
#pragma unroll
      for (int r = 0; r < 4; ++r) {
        int p = p0 + pw0 + mf * 16 + lg * 4 + r;
#pragma unroll
        for (int nf = 0; nf < 8; ++nf) {
          int o = nf * 16 + lr;
          out[(size_t)p * 128 + o] = (_Float16)(acc[mf][nf][r] + bp[o]);
        }
      }
  }
}

// ---------------- flash attention: swapped QK^T (lane owns one q), split-K x2
__global__ __launch_bounds__(512) void attn_kernel(
    const _Float16* __restrict__ th16, const _Float16* __restrict__ ph16,
    const _Float16* __restrict__ g16, _Float16* __restrict__ o16) {
  const int lin = blockIdx.x;  // 256
  const int xcd = lin & 7;     // 2 XCDs per batch
  const int n = xcd >> 1;
  const int qt = ((lin >> 3) << 1) | (xcd & 1);
  const int q0 = qt * 64;
  const int tid = threadIdx.x;
  const int wv = tid >> 6, lane = tid & 63, lg = lane >> 4, lr = lane & 15;
  const int half = wv & 1, qsub = wv >> 1;

  // K 4x16KB + G 4x16KB + P 8x2KB = 144KB
  __shared__ __align__(16) char smem[147456];
#define KBUF(h, b) (smem + ((h)*2 + (b)) * 16384)
#define GBUF(h, b) (smem + 65536 + ((h)*2 + (b)) * 16384)
  char* pB = smem + 131072 + wv * 2048;

  const _Float16* thn = th16 + (size_t)n * 128 * 4096;
  const char* phn = (const char*)(ph16 + (size_t)n * 4096 * 128);
  const char* ggn = (const char*)(g16 + (size_t)n * 128 * 4096);

  const char* ksrc = phn + (tid >> 4) * 256 + (((tid & 15) * 16) ^ (((tid >> 4) & 7) << 4));
  const char* gsrc = ggn + (size_t)(tid >> 3) * 8192 + (((tid & 7) * 16) ^ (((tid >> 3) & 7) << 4));

#define STAGE(KT, B)                                                                     \
  do {                                                                                   \
    _Pragma("unroll") for (int h_ = 0; h_ < 2; ++h_) {                                   \
      const char* ks = ksrc + (size_t)(h_ * 2048 + (KT) * 64) * 256;                     \
      const char* gs = gsrc + (size_t)(h_ * 2048 + (KT) * 64) * 2;                       \
      char* kd = KBUF(h_, B) + tid * 16;                                                 \
      char* gd = GBUF(h_, B) + tid * 16;                                                 \
      __builtin_amdgcn_global_load_lds((as1_u32*)ks, (as3_u32*)kd, 16, 0, 0);            \
      __builtin_amdgcn_global_load_lds((as1_u32*)(ks + 8192), (as3_u32*)(kd + 8192), 16, 0, 0); \
      __builtin_amdgcn_global_load_lds((as1_u32*)gs, (as3_u32*)gd, 16, 0, 0);            \
      __builtin_amdgcn_global_load_lds((as1_u32*)(gs + 524288), (as3_u32*)(gd + 8192), 16, 0, 0); \
    }                                                                                    \
  } while (0)

  // Q fragment (B-operand): B[k=ci][n=q=lr], content Q[q=lr][ci=ch*32+lg*8+j]
  const int q = q0 + qsub * 16 + lr;
  f16x8 qf[4];
#pragma unroll
  for (int ch = 0; ch < 4; ++ch)
#pragma unroll
    for (int j = 0; j < 8; ++j)
      qf[ch][j] = thn[(size_t)(ch * 32 + lg * 8 + j) * 4096 + q];

  const int swzk = (lr & 7) << 4;
  const int swzp = (lr & 15) << 3;

  f32x4 acc[8];
#pragma unroll
  for (int of = 0; of < 8; ++of) acc[of] = f32x4{0.f, 0.f, 0.f, 0.f};
  float mrow = -INFINITY, lrow = 0.f;

  STAGE(0, 0);
  __syncthreads();

  for (int kt = 0; kt < 32; ++kt) {
    const int b = kt & 1;
    if (kt < 31) STAGE(kt + 1, b ^ 1);

    // S^T = K * Q^T : D[k=cf*16+lg*4+r][q=lr]
    const char* kb = KBUF(half, b);
    f32x4 s[4];
    __builtin_amdgcn_s_setprio(1);
#pragma unroll
    for (int cf = 0; cf < 4; ++cf) {
      const char* krow = kb + (cf * 16 + lr) * 256;
      f32x4 sv = f32x4{0.f, 0.f, 0.f, 0.f};
#pragma unroll
      for (int ch = 0; ch < 4; ++ch) {
        f16x8 kf = *(const f16x8*)(krow + ((ch * 64 + lg * 16) ^ swzk));
        sv = __builtin_amdgcn_mfma_f32_16x16x32_f16(kf, qf[ch], sv, 0, 0, 0);
      }
      s[cf] = sv;
    }
    __builtin_amdgcn_s_setprio(0);

    // online softmax, lane-local q
    float mt = s[0][0];
#pragma unroll
    for (int cf = 0; cf < 4; ++cf)
#pragma unroll
      for (int r = 0; r < 4; ++r) mt = fmaxf(mt, s[cf][r]);
    mt = fmaxf(mt, __shfl_xor(mt, 16));
    mt = fmaxf(mt, __shfl_xor(mt, 32));
    if (!__all(mt <= mrow + 8.0f)) {  // defer-max (THR=8)
      float mnew = fmaxf(mrow, mt);
      float sc = __expf(mrow - mnew);
#pragma unroll
      for (int of = 0; of < 8; ++of) acc[of] *= sc;
      lrow *= sc;
      mrow = mnew;
    }
    float psum = 0.f;
    char* prow = pB + lr * 128;
#pragma unroll
    for (int cf = 0; cf < 4; ++cf) {
      float p0 = __expf(s[cf][0] - mrow);
      float p1 = __expf(s[cf][1] - mrow);
      float p2 = __expf(s[cf][2] - mrow);
      float p3 = __expf(s[cf][3] - mrow);
      psum += (p0 + p1) + (p2 + p3);
      unsigned long long w = (unsigned long long)packh2(p0, p1) |
                             ((unsigned long long)packh2(p2, p3) << 32);
      *(unsigned long long*)(prow + ((cf * 32 + lg * 8) ^ swzp)) = w;
    }
    psum += __shfl_xor(psum, 16);
    psum += __shfl_xor(psum, 32);
    lrow += psum;

    // PV: O^T = G * P^T ; D[ci=of*16+lg*4+r][q=lr]
    const char* gb = GBUF(half, b);
    __builtin_amdgcn_s_setprio(1);
#pragma unroll
    for (int kc = 0; kc < 2; ++kc) {
      int b0 = kc * 64 + lg * 16;
      unsigned long long w0 = *(const unsigned long long*)(prow + (b0 ^ swzp));
      unsigned long long w1 = *(const unsigned long long*)(prow + ((b0 + 8) ^ swzp));
      f16x8 pf;
      unsigned* pu = (unsigned*)&pf;
      pu[0] = (unsigned)w0; pu[1] = (unsigned)(w0 >> 32);
      pu[2] = (unsigned)w1; pu[3] = (unsigned)(w1 >> 32);
#pragma unroll
      for (int of = 0; of < 8; ++of) {
        f16x8 gf = *(const f16x8*)(gb + (of * 16 + lr) * 128 + ((kc * 64 + lg * 16) ^ swzk));
        acc[of] = __builtin_amdgcn_mfma_f32_16x16x32_f16(gf, pf, acc[of], 0, 0, 0);
      }
    }
    __builtin_amdgcn_s_setprio(0);
    __syncthreads();  // drains stage(kt+1); all waves done with buf b
  }

  // ----- split-K merge (per-lane scalars: q = lr)
  float* mg = (float*)(smem + qsub * 9216);  // 64 lanes x 36 f32
  if (half == 1) {
#pragma unroll
    for (int of = 0; of < 8; ++of)
#pragma unroll
      for (int r = 0; r < 4; ++r) mg[lane * 36 + of * 4 + r] = acc[of][r];
    mg[lane * 36 + 32] = mrow;
    mg[lane * 36 + 33] = lrow;
  }
  __syncthreads();
  if (half == 0) {
    float pm = mg[lane * 36 + 32];
    float pl = mg[lane * 36 + 33];
    float mm = fmaxf(mrow, pm);
    float a0 = __expf(mrow - mm), a1 = __expf(pm - mm);
    float inv = 1.0f / (lrow * a0 + pl * a1);
#pragma unroll
    for (int of = 0; of < 8; ++of)
#pragma unroll
      for (int r = 0; r < 4; ++r)
        acc[of][r] = (acc[of][r] * a0 + mg[lane * 36 + of * 4 + r] * a1) * inv;
  }
  __syncthreads();
  if (half == 0) {
    // transpose O^T -> [q][ci] through LDS, store fp16 coalesced
    float* ep = (float*)(smem + qsub * 8448);  // 16 rows x 132 f32
#pragma unroll
    for (int of = 0; of < 8; ++of)
#pragma unroll
      for (int r = 0; r < 4; ++r) ep[lr * 132 + of * 16 + lg * 4 + r] = acc[of][r];
    char* on = (char*)(o16 + (size_t)n * 4096 * 128);
#pragma unroll
    for (int it = 0; it < 4; ++it) {
      int e = lane + it * 64;
      int qq = e >> 4, c8 = e & 15;
      f32x4 va = *(const f32x4*)(ep + qq * 132 + c8 * 8);
      f32x4 vb = *(const f32x4*)(ep + qq * 132 + c8 * 8 + 4);
      f16x8 h;
#pragma unroll
      for (int j = 0; j < 4; ++j) { h[j] = (_Float16)va[j]; h[4 + j] = (_Float16)vb[j]; }
      *(f16x8*)(on + (size_t)(q0 + qsub * 16 + qq) * 256 + c8 * 16) = h;
    }
  }
#undef STAGE
#undef KBUF
#undef GBUF
}

// ---------------- rec projection (MFMA) + per-block BN partial stats (no atomics)
__global__ __launch_bounds__(256) void rec_kernel(
    const _Float16* __restrict__ o16, const _Float16* __restrict__ rw16,
    const float* __restrict__ rb, float* __restrict__ out,
    float* __restrict__ partial) {
  const int pblk = blockIdx.x;  // 128 tiles of 32 positions
  const int n = blockIdx.y;
  const int p0 = pblk * 32;
  const int blin = n * 128 + pblk;  // 0..511
  const int tid = threadIdx.x, wv = tid >> 6, lane = tid & 63, lg = lane >> 4, lr = lane & 15;
  __shared__ __align__(16) char sB[8192];  // O tile [32 pos][128 ci] fp16, swizzled
  const char* o16n = (const char*)(o16 + (size_t)n * 4096 * 128);
  const char* srcb = o16n + (size_t)p0 * 256 + (tid >> 4) * 256 +
                     (((tid & 15) * 16) ^ (((tid >> 4) & 7) << 4));
  __builtin_amdgcn_global_load_lds((as1_u32*)srcb, (as3_u32*)(sB + tid * 16), 16, 0, 0);
  __builtin_amdgcn_global_load_lds((as1_u32*)(srcb + 4096), (as3_u32*)(sB + 4096 + tid * 16), 16, 0, 0);

  const int wc0 = wv * 64;
  f16x8 a[4][4];  // W fragments, vector loads (fp16 pre-packed)
#pragma unroll
  for (int mf = 0; mf < 4; ++mf)
#pragma unroll
    for (int kc = 0; kc < 4; ++kc)
      a[mf][kc] = *(const f16x8*)(rw16 + (size_t)(wc0 + mf * 16 + lr) * 128 + kc * 32 + lg * 8);
  __syncthreads();

  f32x4 acc[4][2];
#pragma unroll
  for (int mf = 0; mf < 4; ++mf) {
    acc[mf][0] = f32x4{0.f, 0.f, 0.f, 0.f};
    acc[mf][1] = f32x4{0.f, 0.f, 0.f, 0.f};
  }
  const int xorv = (lr & 7) << 4;
#pragma unroll
  for (int kc = 0; kc < 4; ++kc) {
    int cb = (kc * 64 + lg * 16) ^ xorv;
    f16x8 b0 = *(const f16x8*)(sB + lr * 256 + cb);
    f16x8 b1 = *(const f16x8*)(sB + (16 + lr) * 256 + cb);
#pragma unroll
    for (int mf = 0; mf < 4; ++mf) {
      acc[mf][0] = __builtin_amdgcn_mfma_f32_16x16x32_f16(a[mf][kc], b0, acc[mf][0], 0, 0, 0);
      acc[mf][1] = __builtin_amdgcn_mfma_f32_16x16x32_f16(a[mf][kc], b1, acc[mf][1], 0, 0, 0);
    }
  }
  float* pslot = partial + (size_t)blin * 512;
#pragma unroll
  for (int mf = 0; mf < 4; ++mf)
#pragma unroll
    for (int r = 0; r < 4; ++r) {
      int c = wc0 + mf * 16 + lg * 4 + r;
      float bias = rb[c];
      float v0 = acc[mf][0][r] + bias;
      float v1 = acc[mf][1][r] + bias;
      out[((size_t)n * 256 + c) * 4096 + p0 + lr] = v0;
      out[((size_t)n * 256 + c) * 4096 + p0 + 16 + lr] = v1;
      float s = v0 + v1, qd = v0 * v0 + v1 * v1;
      s += __shfl_xor(s, 1); qd += __shfl_xor(qd, 1);
      s += __shfl_xor(s, 2); qd += __shfl_xor(qd, 2);
      s += __shfl_xor(s, 4); qd += __shfl_xor(qd, 4);
      s += __shfl_xor(s, 8); qd += __shfl_xor(qd, 8);
      if (lr == 0) {
        pslot[c] = s;
        pslot[256 + c] = qd;
      }
    }
}

// ---------------- reduce per-block partials -> stats[512]
__global__ __launch_bounds__(256) void stats_reduce(const float* __restrict__ partial,
                                                    float* __restrict__ stats) {
  const int j = blockIdx.x * 256 + threadIdx.x;  // 0..511
  float s = 0.f;
#pragma unroll 8
  for (int b = 0; b < 512; ++b) s += partial[(size_t)b * 512 + j];
  stats[j] = s;
}

// ---------------- BN apply + residual
__global__ __launch_bounds__(256) void bn_kernel(
    const float* __restrict__ x, const float* __restrict__ gamma,
    const float* __restrict__ beta, const float* __restrict__ stats,
    float* __restrict__ out) {
  const size_t i4 = (size_t)blockIdx.x * 256 + threadIdx.x;
  const int c = (int)((i4 >> 10) & 255);
  const float inv = 1.f / 16384.f;
  const float mean = stats[c] * inv;
  const float var = stats[256 + c] * inv - mean * mean;
  const float gm = gamma[c] * rsqrtf(var + EPSV);
  const float bt = beta[c];
  float4 rv = ((const float4*)out)[i4];
  float4 xv = ((const float4*)x)[i4];
  float4 o;
  o.x = xv.x + (rv.x - mean) * gm + bt;
  o.y = xv.y + (rv.y - mean) * gm + bt;
  o.z = xv.z + (rv.z - mean) * gm + bt;
  o.w = xv.w + (rv.w - mean) * gm + bt;
  ((float4*)out)[i4] = o;
}

extern "C" void kernel_launch(void* const* d_in, const int* in_sizes, int n_in,
                              void* d_out, int out_size, void* d_ws, size_t ws_size,
                              hipStream_t stream) {
  const float* x  = (const float*)d_in[0];
  const float* y  = (const float*)d_in[1];
  const float* tw = (const float*)d_in[2];
  const float* tb = (const float*)d_in[3];
  const float* pw = (const float*)d_in[4];
  const float* pb = (const float*)d_in[5];
  const float* gw = (const float*)d_in[6];
  const float* gb = (const float*)d_in[7];
  const float* rw = (const float*)d_in[8];
  const float* rb = (const float*)d_in[9];
  const float* gamma = (const float*)d_in[10];
  const float* beta  = (const float*)d_in[11];
  float* out = (float*)d_out;
  _Float16* xt   = (_Float16*)d_ws;        // 16MB [2][4][4096][256]
  _Float16* w16  = xt + 8388608;           // 256KB [4][32768]
  _Float16* th16 = w16 + 131072;           // 4MB [n][ci][p]
  _Float16* ph16 = th16 + 2097152;         // 4MB [n][p][ci]
  _Float16* g16  = ph16 + 2097152;         // 4MB [n][ci][p]
  _Float16* o16  = g16 + 2097152;          // 4MB [n][q][ci]
  float* partial = (float*)(o16 + 2097152);  // 1MB [512][512]
  float* stats   = partial + 262144;         // 512 f32
  _Float16* rw16 = w16 + 98304;
  pack_w<<<dim3(512), 256, 0, stream>>>(tw, pw, gw, rw, w16);
  pack_xy<<<dim3(512, 4, 2), 256, 0, stream>>>(x, y, xt);
  proj_kernel<<<dim3(32, 12), 256, 0, stream>>>(xt, w16, tb, pb, gb, th16, ph16, g16);
  attn_kernel<<<dim3(256), 512, 0, stream>>>(th16, ph16, g16, o16);
  rec_kernel<<<dim3(128, 4), 256, 0, stream>>>(o16, rw16, rb, out, partial);
  stats_reduce<<<dim3(2), 256, 0, stream>>>(partial, stats);
  bn_kernel<<<dim3(4096), 256, 0, stream>>>(x, gamma, beta, stats, out);
}